// Round 6
// baseline (270.085 us; speedup 1.0000x reference)
//
#include <hip/hip_runtime.h>
#include <hip/hip_bf16.h>
#include <math.h>

#define DM   1024
#define SEQ  2048
#define NH   16
#define HD   64
#define BATCH 4

// Q pre-scaled by 1/sqrt(HD)*log2(e) in the Q-GEMM epilogue; attn uses exp2.
#define QSCALE 0.180336879f

typedef __attribute__((ext_vector_type(8))) short bf16x8;
typedef __attribute__((ext_vector_type(4))) short short4v;
typedef __attribute__((ext_vector_type(4))) float f32x4;
typedef __attribute__((ext_vector_type(4))) float float4v;

// counted waitcnt (T4): literal-only macro
#define S_VMCNT(n) asm volatile("s_waitcnt vmcnt(" #n ")" ::: "memory")
#define BARRIER    asm volatile("s_barrier" ::: "memory")
#define SCHEDB     __builtin_amdgcn_sched_barrier(0)

static __device__ inline short f2bf(float f) {    // RNE
  union { float f; unsigned u; } v; v.f = f;
  unsigned u = v.u + 0x7fff + ((v.u >> 16) & 1);
  return (short)(u >> 16);
}

// async global->LDS, 16B/lane; LDS dest = wave-uniform base + lane*16
static __device__ __forceinline__ void async16(const void* g, void* l) {
  __builtin_amdgcn_global_load_lds(
      (const __attribute__((address_space(1))) void*)g,
      (__attribute__((address_space(3))) void*)l, 16, 0, 0);
}

// ---------------------------------------------------------------------------
// One-shot conversion to bf16 (RNE, hi only): x, kv, Wq, Wk, Wv, Wo.
// ---------------------------------------------------------------------------
__global__ void conv_all(const float* __restrict__ x, const float* __restrict__ kv,
                         const float* __restrict__ Wq, const float* __restrict__ Wk,
                         const float* __restrict__ Wv, const float* __restrict__ Wo,
                         short* __restrict__ xh, short* __restrict__ kvh,
                         short* __restrict__ Wqh, short* __restrict__ Wkh,
                         short* __restrict__ Wvh, short* __restrict__ Woh)
{
  const int blk = blockIdx.x;
  const float* src; short* hi; int base;
  if (blk < 8192)       { src = x;  hi = xh;  base = blk; }
  else if (blk < 16384) { src = kv; hi = kvh; base = blk - 8192; }
  else {
    int wi = (blk - 16384) >> 10; base = (blk - 16384) & 1023;
    src = wi == 0 ? Wq : wi == 1 ? Wk : wi == 2 ? Wv : Wo;
    hi  = wi == 0 ? Wqh : wi == 1 ? Wkh : wi == 2 ? Wvh : Woh;
  }
  int i = base * 1024 + threadIdx.x * 4;
  float4v v = *(const float4v*)(src + i);
  short4v h;
#pragma unroll
  for (int j = 0; j < 4; j++) h[j] = f2bf(v[j]);
  *(short4v*)(hi + i) = h;
}

// ---------------------------------------------------------------------------
// 8-PHASE 256x256 QKV GEMM (T2+T3+T4+T5 full stack, m201 template geometry).
// 512 thr = 8 waves (2M x 4N), BK=64, per-wave C = 128x64 (8mt x 4nt frags).
// LDS 128 KB: buf b at b*32768 shorts:
//   A + 0:     [mblk(2)][wr(2)][64 rows][64 cols]   (mblk = mt>>2 half)
//   B + 16384: [nblk(2)][wc(4)][32 rows][64 cols]   (nblk = nt>>1 half)
// Half-tiles defined by READ phase: A-a = mt-lo rows (read P0), A-b = mt-hi
// (read P2), B-a = nt-lo (read P0), B-b = nt-hi (read P1).  2 async16/thread
// per half-tile.  Per K-tile t (4 phases, one C-quadrant x K=64 each):
//   P0: ds a_lo(8)+b_lo(4); issue A-b(t+1); BAR; 16 MFMA; BAR
//   P1: ds b_hi(4);         issue A-a(t+2); BAR; 16 MFMA; BAR
//   P2: ds a_hi(8);         issue B-a(t+2); BAR; 16 MFMA; BAR
//   P3:                     issue B-b(t+2); BAR; 16 MFMA; vmcnt(6); BAR
// Race ledger: each issue overwrites a region whose reads retired >=1
// barrier earlier (reads are consumed by same-phase MFMA -> retired by that
// phase's trailing barrier).  vmcnt(6) at P3 = 3 half-tiles (6 loads) in
// flight -> K-tile t+1 fully landed before its first read.  Prologue: 7
// half-tiles + vmcnt(6).  Epilogue: vmcnt(0) at t==NKT-2.  Swizzle: proven
// XOR scheme (global chunk ^= srow&7; read col ^= (r15&7)*8) -> 0 conflicts.
// Grid 384 flat: gid = n*96 + (m*3+z) -> 4 A-panel sharers co-located per XCD.
// ---------------------------------------------------------------------------
__global__ __launch_bounds__(512, 2)
void gemm_qkv8(const short* __restrict__ xh, const short* __restrict__ kvh,
               const short* __restrict__ Wqh, const short* __restrict__ Wkh,
               const short* __restrict__ Wvh,
               short* __restrict__ Qh, short* __restrict__ Kh, short* __restrict__ Vt)
{
  __shared__ short lds[65536];                 // 128 KB

  const int gid = blockIdx.x;                  // 0..383
  const int nblk = gid / 96;
  const int rm   = gid - nblk * 96;
  const int mblk = rm / 3, z = rm - mblk * 3;
  const short* Ag = (z == 0) ? xh : kvh;
  const short* Bw = (z == 0) ? Wqh : (z == 1) ? Wkh : Wvh;
  const int m0 = mblk * 256, n0 = nblk * 256;

  const int t = threadIdx.x;
  const int lane = t & 63, w = t >> 6;         // 8 waves
  const int r15 = lane & 15, quad = lane >> 4;
  const int wr = w >> 2, wc = w & 3;           // 2M x 4N
  const int srow = t >> 3;                     // 0..63
  const int spg  = ((t & 7) ^ (srow & 7)) * 8; // pre-swizzled k-chunk (shorts)
  const int swb  = (r15 & 7) * 8;
  const int NKT  = DM / 64;                    // 16 K-tiles

  auto stageA = [&](int kt, int mb) {          // one A half-tile (2 loads)
    const short* src = Ag + (size_t)(m0 + mb * 64 + srow) * DM + kt * 64 + spg;
    short* dst = &lds[(kt & 1) * 32768 + mb * 8192 + t * 8];
    async16(src,            dst);              // wr = 0 rows
    async16(src + 128 * DM, dst + 4096);       // wr = 1 rows
  };
  auto stageB = [&](int kt, int nb) {          // one B half-tile (2 loads)
    const short* src = Bw + (size_t)(n0 + (t >> 8) * 64 + nb * 32 + (srow & 31)) * DM
                          + kt * 64 + spg;
    short* dst = &lds[(kt & 1) * 32768 + 16384 + nb * 8192 + t * 8];
    async16(src,            dst);              // wc groups 0,1
    async16(src + 128 * DM, dst + 4096);       // wc groups 2,3
  };

  f32x4 acc[8][4];
#pragma unroll
  for (int i = 0; i < 8; i++)
#pragma unroll
    for (int j = 0; j < 4; j++) acc[i][j] = (f32x4)0.0f;

  // ---- prologue: K-tile 0 (4 halves) + 3 halves of K-tile 1 ----
  stageA(0, 0); stageB(0, 0); stageB(0, 1); stageA(0, 1);
  stageA(1, 0); stageB(1, 0); stageB(1, 1);
  S_VMCNT(6);                                  // K-tile 0 fully landed
  BARRIER; SCHEDB;

  bf16x8 a_lo[4][2], a_hi[4][2], b_lo[2][2], b_hi[2][2];

  for (int kt = 0; kt < NKT; kt++) {
    const int bb = (kt & 1) * 32768;

    // ================= P0: quadrant (mt-lo, nt-lo) =================
#pragma unroll
    for (int mt = 0; mt < 4; mt++)
#pragma unroll
      for (int ks = 0; ks < 2; ks++)
        a_lo[mt][ks] = *(const bf16x8*)&lds[bb + wr * 4096 + (mt * 16 + r15) * 64
                                           + (((ks * 4 + quad) * 8) ^ swb)];
#pragma unroll
    for (int nt = 0; nt < 2; nt++)
#pragma unroll
      for (int ks = 0; ks < 2; ks++)
        b_lo[nt][ks] = *(const bf16x8*)&lds[bb + 16384 + wc * 2048 + (nt * 16 + r15) * 64
                                            + (((ks * 4 + quad) * 8) ^ swb)];
    if (kt + 1 < NKT) stageA(kt + 1, 1);       // A-b(t+1): A-b(t) read P2(t-1)
    BARRIER; SCHEDB;
    __builtin_amdgcn_s_setprio(1);
#pragma unroll
    for (int mt = 0; mt < 4; mt++)
#pragma unroll
      for (int nt = 0; nt < 2; nt++) {
        acc[mt][nt] = __builtin_amdgcn_mfma_f32_16x16x32_bf16(a_lo[mt][0], b_lo[nt][0], acc[mt][nt], 0, 0, 0);
        acc[mt][nt] = __builtin_amdgcn_mfma_f32_16x16x32_bf16(a_lo[mt][1], b_lo[nt][1], acc[mt][nt], 0, 0, 0);
      }
    __builtin_amdgcn_s_setprio(0);
    SCHEDB; BARRIER; SCHEDB;

    // ================= P1: quadrant (mt-lo, nt-hi) =================
#pragma unroll
    for (int nt = 0; nt < 2; nt++)
#pragma unroll
      for (int ks = 0; ks < 2; ks++)
        b_hi[nt][ks] = *(const bf16x8*)&lds[bb + 16384 + 8192 + wc * 2048 + (nt * 16 + r15) * 64
                                            + (((ks * 4 + quad) * 8) ^ swb)];
    if (kt + 2 < NKT) stageA(kt + 2, 0);       // A-a(t+2): A-a(t) read P0(t)
    BARRIER; SCHEDB;
    __builtin_amdgcn_s_setprio(1);
#pragma unroll
    for (int mt = 0; mt < 4; mt++)
#pragma unroll
      for (int nt = 0; nt < 2; nt++) {
        acc[mt][2 + nt] = __builtin_amdgcn_mfma_f32_16x16x32_bf16(a_lo[mt][0], b_hi[nt][0], acc[mt][2 + nt], 0, 0, 0);
        acc[mt][2 + nt] = __builtin_amdgcn_mfma_f32_16x16x32_bf16(a_lo[mt][1], b_hi[nt][1], acc[mt][2 + nt], 0, 0, 0);
      }
    __builtin_amdgcn_s_setprio(0);
    SCHEDB; BARRIER; SCHEDB;

    // ================= P2: quadrant (mt-hi, nt-lo) =================
#pragma unroll
    for (int mt = 0; mt < 4; mt++)
#pragma unroll
      for (int ks = 0; ks < 2; ks++)
        a_hi[mt][ks] = *(const bf16x8*)&lds[bb + 8192 + wr * 4096 + (mt * 16 + r15) * 64
                                            + (((ks * 4 + quad) * 8) ^ swb)];
    if (kt + 2 < NKT) stageB(kt + 2, 0);       // B-a(t+2): B-a(t) read P0(t)
    BARRIER; SCHEDB;
    __builtin_amdgcn_s_setprio(1);
#pragma unroll
    for (int mt = 0; mt < 4; mt++)
#pragma unroll
      for (int nt = 0; nt < 2; nt++) {
        acc[4 + mt][nt] = __builtin_amdgcn_mfma_f32_16x16x32_bf16(a_hi[mt][0], b_lo[nt][0], acc[4 + mt][nt], 0, 0, 0);
        acc[4 + mt][nt] = __builtin_amdgcn_mfma_f32_16x16x32_bf16(a_hi[mt][1], b_lo[nt][1], acc[4 + mt][nt], 0, 0, 0);
      }
    __builtin_amdgcn_s_setprio(0);
    SCHEDB; BARRIER; SCHEDB;

    // ================= P3: quadrant (mt-hi, nt-hi) =================
    if (kt + 2 < NKT) stageB(kt + 2, 1);       // B-b(t+2): B-b(t) read P1(t)
    BARRIER; SCHEDB;
    __builtin_amdgcn_s_setprio(1);
#pragma unroll
    for (int mt = 0; mt < 4; mt++)
#pragma unroll
      for (int nt = 0; nt < 2; nt++) {
        acc[4 + mt][2 + nt] = __builtin_amdgcn_mfma_f32_16x16x32_bf16(a_hi[mt][0], b_hi[nt][0], acc[4 + mt][2 + nt], 0, 0, 0);
        acc[4 + mt][2 + nt] = __builtin_amdgcn_mfma_f32_16x16x32_bf16(a_hi[mt][1], b_hi[nt][1], acc[4 + mt][2 + nt], 0, 0, 0);
      }
    __builtin_amdgcn_s_setprio(0);
    SCHEDB;
    if (kt < NKT - 2)       { S_VMCNT(6); }    // K-tile t+1 landed, 3 halves in flight
    else if (kt == NKT - 2) { S_VMCNT(0); }    // drain for final tile
    BARRIER; SCHEDB;
  }

  // ---- epilogue ----
  if (z < 2) {
    short* Cp = (z == 0) ? Qh : Kh;
    const float scale = (z == 0) ? QSCALE : 1.0f;
#pragma unroll
    for (int mt = 0; mt < 8; mt++)
#pragma unroll
      for (int nt = 0; nt < 4; nt++)
#pragma unroll
        for (int reg = 0; reg < 4; reg++) {
          int m = m0 + wr * 128 + mt * 16 + quad * 4 + reg;
          int n = n0 + wc * 64 + nt * 16 + r15;
          Cp[(size_t)m * DM + n] = f2bf(acc[mt][nt][reg] * scale);
        }
  } else {
    // V: [b][d][sigma(s)], sigma within each 64-block: (kl&15)*4 + kl>>4
#pragma unroll
    for (int mt = 0; mt < 8; mt++)
#pragma unroll
      for (int nt = 0; nt < 4; nt++)
#pragma unroll
        for (int reg = 0; reg < 4; reg++) {
          int m = m0 + wr * 128 + mt * 16 + quad * 4 + reg;
          int n = n0 + wc * 64 + nt * 16 + r15;
          int s = m & (SEQ - 1), kl = s & 63;
          int sp = (s & ~63) + ((kl & 15) * 4 + (kl >> 4));
          Vt[((size_t)(m >> 11) * DM + n) * SEQ + sp] = f2bf(acc[mt][nt][reg]);
        }
  }
}

// ---------------------------------------------------------------------------
// Proven 128x128 GEMM core (2-phase counted-vmcnt) — kept for gemm_out.
// ---------------------------------------------------------------------------
static __device__ __forceinline__ void gemm_core(
    const short* __restrict__ A, const short* __restrict__ Bh,
    short* __restrict__ As, short* __restrict__ Bs,
    int m0, int n0, f32x4 acc[4][4])
{
  const int t = threadIdx.x;
  const int lane = t & 63, w = t >> 6;
  const int r15 = lane & 15, quad = lane >> 4;
  const int wm = (w & 1) * 64, wn = (w >> 1) * 64;
  const int srow = t >> 3;
  const int spg = ((t & 7) ^ (srow & 7)) * 8;
  const int swb = (r15 & 7) * 8;
  const int NT = DM / 64;

#pragma unroll
  for (int i = 0; i < 4; i++)
#pragma unroll
    for (int j = 0; j < 4; j++) acc[i][j] = (f32x4)0.0f;

  auto stage = [&](int kt, int bufi) {
    const int k0 = kt * 64;
    short* Ad = As + bufi * 8192 + t * 8;
    short* Bd = Bs + bufi * 8192 + t * 8;
#pragma unroll
    for (int i = 0; i < 4; i++) {
      async16(A  + (size_t)(m0 + srow + 32 * i) * DM + k0 + spg, Ad + i * 2048);
      async16(Bh + (size_t)(n0 + srow + 32 * i) * DM + k0 + spg, Bd + i * 2048);
    }
  };

  stage(0, 0);
  stage(1, 1);

  for (int kt = 0; kt < NT; kt++) {
    const int cur = kt & 1;
    if (kt + 1 < NT) { S_VMCNT(8); } else { S_VMCNT(0); }
    __builtin_amdgcn_s_barrier();
    __builtin_amdgcn_sched_barrier(0);

    const short* Ab = As + cur * 8192;
    const short* Bb = Bs + cur * 8192;
    bf16x8 ah[4][2], bh[4][2];
#pragma unroll
    for (int mt = 0; mt < 4; mt++) {
      const int ro = (wm + mt * 16 + r15) * 64;
#pragma unroll
      for (int ks = 0; ks < 2; ks++)
        ah[mt][ks] = *(const bf16x8*)&Ab[ro + (((ks * 4 + quad) * 8) ^ swb)];
    }
#pragma unroll
    for (int nt = 0; nt < 4; nt++) {
      const int ro = (wn + nt * 16 + r15) * 64;
#pragma unroll
      for (int ks = 0; ks < 2; ks++)
        bh[nt][ks] = *(const bf16x8*)&Bb[ro + (((ks * 4 + quad) * 8) ^ swb)];
    }

    __builtin_amdgcn_s_setprio(1);
#pragma unroll
    for (int mt = 0; mt < 4; mt++)
#pragma unroll
      for (int nt = 0; nt < 4; nt++) {
        acc[mt][nt] = __builtin_amdgcn_mfma_f32_16x16x32_bf16(ah[mt][0], bh[nt][0], acc[mt][nt], 0, 0, 0);
        acc[mt][nt] = __builtin_amdgcn_mfma_f32_16x16x32_bf16(ah[mt][1], bh[nt][1], acc[mt][nt], 0, 0, 0);
      }
    __builtin_amdgcn_s_setprio(0);

    __builtin_amdgcn_s_barrier();
    __builtin_amdgcn_sched_barrier(0);
    if (kt + 2 < NT) stage(kt + 2, cur);
  }
}

// Output projection: ctx(bf16) x Wo^T -> fp32 row-major.  FLAT grid of 512:
//   gid = x*64 + y  ->  gid%8 == y%8 for all 8 x-blocks (A-panel co-location).
__global__ __launch_bounds__(256, 2)
void gemm_out(const short* __restrict__ ctx, const short* __restrict__ Woh,
              float* __restrict__ out)
{
  __shared__ short As[2][8192];
  __shared__ short Bs[2][8192];
  const int gid = blockIdx.x;
  const int xblk = gid >> 6;
  const int yblk = gid & 63;
  const int m0 = yblk * 128, n0 = xblk * 128;
  f32x4 acc[4][4];
  gemm_core(ctx, Woh, &As[0][0], &Bs[0][0], m0, n0, acc);

  const int t = threadIdx.x, lane = t & 63, w = t >> 6;
  const int r15 = lane & 15, quad = lane >> 4;
  const int wm = (w & 1) * 64, wn = (w >> 1) * 64;
#pragma unroll
  for (int mt = 0; mt < 4; mt++)
#pragma unroll
    for (int nt = 0; nt < 4; nt++)
#pragma unroll
      for (int reg = 0; reg < 4; reg++) {
        int m = m0 + wm + mt * 16 + quad * 4 + reg;
        int n = n0 + wn + nt * 16 + r15;
        out[(size_t)m * DM + n] = acc[mt][nt][reg];
      }
}

// ---------------------------------------------------------------------------
// Causal flash attention (unchanged, session-proven).
// ---------------------------------------------------------------------------
__global__ __launch_bounds__(256, 3)
void attn(const short* __restrict__ Qh_g, const short* __restrict__ Kh_g,
          const short* __restrict__ Vt_g, short* __restrict__ ctx)
{
  __shared__ short KV[2][2 * 4096];   // [Kh | V], 16 KB per buffer
  __shared__ short Plds[4][32][72];

  const int t = threadIdx.x, lane = t & 63, w = t >> 6;
  const int r15 = lane & 15, quad = lane >> 4;
  const int bh = blockIdx.x, b = bh >> 4, h = bh & 15;
  const int qt = 15 - blockIdx.y;     // heavy-first dispatch
  const int qw = qt * 128 + w * 32;
  const int nkt = 2 * qt + 2;

  const int srow = t >> 3, spg = (t & 7) ^ (srow & 7);
  const int swb = (r15 & 7) * 8;

  const bf16x8 ones = {0x3F80, 0x3F80, 0x3F80, 0x3F80, 0x3F80, 0x3F80, 0x3F80, 0x3F80};

  bf16x8 qh[2][2];
#pragma unroll
  for (int mt = 0; mt < 2; mt++)
#pragma unroll
    for (int ks = 0; ks < 2; ks++)
      qh[mt][ks] = *(const bf16x8*)(Qh_g + (size_t)(b * SEQ + qw + mt * 16 + r15) * DM
                                    + h * HD + ks * 32 + quad * 8);

  f32x4 o[2][4], ol[2];
#pragma unroll
  for (int mt = 0; mt < 2; mt++) {
    ol[mt] = (f32x4)0.0f;
#pragma unroll
    for (int dt = 0; dt < 4; dt++) o[mt][dt] = (f32x4)0.0f;
  }

  auto stage = [&](int kt, int bufi) {
    short* L = &KV[bufi][0];
    size_t kro = (size_t)(b * SEQ + kt * 64 + srow) * DM + h * HD + spg * 8;
    async16(Kh_g + kro,           L + t * 8);
    async16(Kh_g + kro + 32 * DM, L + 2048 + t * 8);
    size_t vro = (size_t)(b * DM + h * HD + srow) * SEQ + kt * 64 + spg * 8;
    async16(Vt_g + vro,            L + 4096 + t * 8);
    async16(Vt_g + vro + 32 * SEQ, L + 6144 + t * 8);
  };

  stage(0, 0);

  for (int kt = 0; kt < nkt; kt++) {
    __syncthreads();
    if (kt + 1 < nkt) stage(kt + 1, (kt + 1) & 1);
    const short* L = &KV[kt & 1][0];
    const int k0 = kt * 64;
    if (k0 > qw + 31) continue;

    f32x4 s[2][4];
#pragma unroll
    for (int nt = 0; nt < 4; nt++) {
      const int kb = k0 + nt * 16;
      if (kb <= qw + 31) {
        const int ro = (nt * 16 + r15) * 64;
        bf16x8 kh0 = *(const bf16x8*)&L[ro + ((quad * 8) ^ swb)];
        bf16x8 kh1 = *(const bf16x8*)&L[ro + (((4 + quad) * 8) ^ swb)];
        f32x4 a1 = (f32x4)0.0f;
        a1 = __builtin_amdgcn_mfma_f32_16x16x32_bf16(qh[1][0], kh0, a1, 0, 0, 0);
        a1 = __builtin_amdgcn_mfma_f32_16x16x32_bf16(qh[1][1], kh1, a1, 0, 0, 0);
        s[1][nt] = a1;
        if (kb <= qw + 15) {
          f32x4 a0 = (f32x4)0.0f;
          a0 = __builtin_amdgcn_mfma_f32_16x16x32_bf16(qh[0][0], kh0, a0, 0, 0, 0);
          a0 = __builtin_amdgcn_mfma_f32_16x16x32_bf16(qh[0][1], kh1, a0, 0, 0, 0);
          s[0][nt] = a0;
        } else {
          s[0][nt] = (f32x4)(-3e38f);
        }
      } else {
        s[0][nt] = (f32x4)(-3e38f);
        s[1][nt] = (f32x4)(-3e38f);
      }
    }

    unsigned up[2][4][2];
    if (k0 + 63 <= qw) {
#pragma unroll
      for (int mt = 0; mt < 2; mt++)
#pragma unroll
        for (int r = 0; r < 4; r++)
#pragma unroll
          for (int nt = 0; nt < 4; nt++) {
            unsigned pu = __float_as_uint(__builtin_amdgcn_exp2f(s[mt][nt][r]));
            if ((nt & 1) == 0) up[mt][r][nt >> 1] = pu >> 16;
            else               up[mt][r][nt >> 1] |= (pu & 0xFFFF0000u);
          }
    } else {
#pragma unroll
      for (int mt = 0; mt < 2; mt++)
#pragma unroll
        for (int r = 0; r < 4; r++) {
          const int qg = qw + mt * 16 + quad * 4 + r;
#pragma unroll
          for (int nt = 0; nt < 4; nt++) {
            float p = __builtin_amdgcn_exp2f(s[mt][nt][r]);
            p = ((k0 + nt * 16 + r15) > qg) ? 0.0f : p;
            unsigned pu = __float_as_uint(p);
            if ((nt & 1) == 0) up[mt][r][nt >> 1] = pu >> 16;
            else               up[mt][r][nt >> 1] |= (pu & 0xFFFF0000u);
          }
        }
    }

#pragma unroll
    for (int mt = 0; mt < 2; mt++)
#pragma unroll
      for (int r = 0; r < 4; r++)
        *(int2*)&Plds[w][mt * 16 + quad * 4 + r][r15 * 4] =
            make_int2((int)up[mt][r][0], (int)up[mt][r][1]);

#pragma unroll
    for (int ks = 0; ks < 2; ks++) {
      bf16x8 pa0 = *(const bf16x8*)&Plds[w][r15][ks * 32 + quad * 8];
      bf16x8 pa1 = *(const bf16x8*)&Plds[w][16 + r15][ks * 32 + quad * 8];
      ol[0] = __builtin_amdgcn_mfma_f32_16x16x32_bf16(pa0, ones, ol[0], 0, 0, 0);
      ol[1] = __builtin_amdgcn_mfma_f32_16x16x32_bf16(pa1, ones, ol[1], 0, 0, 0);
#pragma unroll
      for (int dt = 0; dt < 4; dt++) {
        bf16x8 vb = *(const bf16x8*)&L[4096 + (dt * 16 + r15) * 64 + (((ks * 4 + quad) * 8) ^ swb)];
        o[0][dt] = __builtin_amdgcn_mfma_f32_16x16x32_bf16(pa0, vb, o[0][dt], 0, 0, 0);
        o[1][dt] = __builtin_amdgcn_mfma_f32_16x16x32_bf16(pa1, vb, o[1][dt], 0, 0, 0);
      }
    }
  }

#pragma unroll
  for (int mt = 0; mt < 2; mt++)
#pragma unroll
    for (int r = 0; r < 4; r++) {
      float inv = 1.0f / ol[mt][r];
      int qrow = qw + mt * 16 + quad * 4 + r;
#pragma unroll
      for (int dt = 0; dt < 4; dt++)
        ctx[((size_t)(b * SEQ + qrow)) * DM + h * HD + dt * 16 + r15] =
            f2bf(o[mt][dt][r] * inv);
    }
}

// ---------------------------------------------------------------------------
extern "C" void kernel_launch(void* const* d_in, const int* in_sizes, int n_in,
                              void* d_out, int out_size, void* d_ws, size_t ws_size,
                              hipStream_t stream)
{
  const float* x  = (const float*)d_in[0];
  const float* kv = (const float*)d_in[1];
  // d_in[2] = causal mask, hardcoded
  const float* Wq = (const float*)d_in[3];
  const float* Wk = (const float*)d_in[4];
  const float* Wv = (const float*)d_in[5];
  const float* Wo = (const float*)d_in[6];

  char* ws = (char*)d_ws;
  const size_t SZ  = (size_t)BATCH * SEQ * DM * sizeof(short);  // 16 MB
  const size_t WSZ = (size_t)DM * DM * sizeof(short);           // 2 MB
  short* xh  = (short*)(ws + 0 * SZ);   // dead after Q-GEMM; reused as ctx
  short* kvh = (short*)(ws + 1 * SZ);
  short* Qh  = (short*)(ws + 2 * SZ);
  short* Kh  = (short*)(ws + 3 * SZ);
  short* Vt  = (short*)(ws + 4 * SZ);
  short* ctx = (short*)(ws + 0 * SZ);
  char*  wb  = ws + 5 * SZ;
  short* Wqh = (short*)(wb + 0 * WSZ);
  short* Wkh = (short*)(wb + 1 * WSZ);
  short* Wvh = (short*)(wb + 2 * WSZ);
  short* Woh = (short*)(wb + 3 * WSZ);  // total ws use: 88 MB

  conv_all<<<20480, 256, 0, stream>>>(x, kv, Wq, Wk, Wv, Wo,
                                      xh, kvh, Wqh, Wkh, Wvh, Woh);

  // 8-phase 256^2: 384 blocks, gid = n*96 + (m*3+z) -> A-sharers per XCD
  gemm_qkv8<<<384, 512, 0, stream>>>(xh, kvh, Wqh, Wkh, Wvh, Qh, Kh, Vt);

  dim3 ga(NH * BATCH, 16);                   // x = b*16+h (XCD locality), y -> qt
  attn<<<ga, 256, 0, stream>>>(Qh, Kh, Vt, ctx);

  // flat 512: gid = x*64 + y -> A-panel (ctx) sharers co-located per XCD
  gemm_out<<<512, 256, 0, stream>>>(ctx, Woh, (float*)d_out);
}

// Round 7
// 266.021 us; speedup vs baseline: 1.0153x; 1.0153x over previous
//
#include <hip/hip_runtime.h>
#include <hip/hip_bf16.h>
#include <math.h>

#define DM   1024
#define SEQ  2048
#define NH   16
#define HD   64
#define BATCH 4

// Q pre-scaled by 1/sqrt(HD)*log2(e) in the Q-GEMM epilogue; attn uses exp2.
#define QSCALE 0.180336879f

typedef __attribute__((ext_vector_type(8))) short bf16x8;
typedef __attribute__((ext_vector_type(4))) short short4v;
typedef __attribute__((ext_vector_type(4))) float f32x4;
typedef __attribute__((ext_vector_type(4))) float float4v;

// counted waitcnt (T4): literal-only macro
#define S_VMCNT(n) asm volatile("s_waitcnt vmcnt(" #n ")" ::: "memory")

static __device__ inline short f2bf(float f) {    // RNE
  union { float f; unsigned u; } v; v.f = f;
  unsigned u = v.u + 0x7fff + ((v.u >> 16) & 1);
  return (short)(u >> 16);
}

// pack two fp32 -> one dword of 2x bf16 (RNE), single VALU op (T12 primitive)
static __device__ __forceinline__ unsigned cvt_pk_bf16(float lo, float hi) {
  unsigned u;
  asm("v_cvt_pk_bf16_f32 %0, %1, %2" : "=v"(u) : "v"(lo), "v"(hi));
  return u;
}

// async global->LDS, 16B/lane; LDS dest = wave-uniform base + lane*16
static __device__ __forceinline__ void async16(const void* g, void* l) {
  __builtin_amdgcn_global_load_lds(
      (const __attribute__((address_space(1))) void*)g,
      (__attribute__((address_space(3))) void*)l, 16, 0, 0);
}

// ---------------------------------------------------------------------------
// One-shot conversion to bf16 (RNE, hi only): x, kv, Wq, Wk, Wv, Wo.
// Flat grid: [0,8192) x, [8192,16384) kv, then 4x1024 blocks for weights.
// ---------------------------------------------------------------------------
__global__ void conv_all(const float* __restrict__ x, const float* __restrict__ kv,
                         const float* __restrict__ Wq, const float* __restrict__ Wk,
                         const float* __restrict__ Wv, const float* __restrict__ Wo,
                         short* __restrict__ xh, short* __restrict__ kvh,
                         short* __restrict__ Wqh, short* __restrict__ Wkh,
                         short* __restrict__ Wvh, short* __restrict__ Woh)
{
  const int blk = blockIdx.x;
  const float* src; short* hi; int base;
  if (blk < 8192)       { src = x;  hi = xh;  base = blk; }
  else if (blk < 16384) { src = kv; hi = kvh; base = blk - 8192; }
  else {
    int wi = (blk - 16384) >> 10; base = (blk - 16384) & 1023;
    src = wi == 0 ? Wq : wi == 1 ? Wk : wi == 2 ? Wv : Wo;
    hi  = wi == 0 ? Wqh : wi == 1 ? Wkh : wi == 2 ? Wvh : Woh;
  }
  int i = base * 1024 + threadIdx.x * 4;
  float4v v = *(const float4v*)(src + i);
  short4v h;
#pragma unroll
  for (int j = 0; j < 4; j++) h[j] = f2bf(v[j]);
  *(short4v*)(hi + i) = h;
}

// ---------------------------------------------------------------------------
// GEMM core: C[128,128] tile of A[M,K] * B[N,K]^T.  BK=64, 2 LDS buffers,
// 2-tiles-deep async pipeline with COUNTED vmcnt (T4: never drain in-loop).
// setprio(1) around MFMA cluster (T5).  Swizzle: global chunk pre-swizzled
// by row&7, reads XOR (r15&7)*8 -> measured 0 bank conflicts.
// T1: callers decode a FLAT grid so the n-blocks sharing one A-panel land on
// the SAME XCD (xcd = linear_id % 8) -> FETCH_SIZE 199.7 -> 104.7 MB (r5).
// ---------------------------------------------------------------------------
static __device__ __forceinline__ void gemm_core(
    const short* __restrict__ A, const short* __restrict__ Bh,
    short* __restrict__ As, short* __restrict__ Bs,
    int m0, int n0, f32x4 acc[4][4])
{
  const int t = threadIdx.x;
  const int lane = t & 63, w = t >> 6;
  const int r15 = lane & 15, quad = lane >> 4;
  const int wm = (w & 1) * 64, wn = (w >> 1) * 64;
  const int srow = t >> 3;
  const int spg = ((t & 7) ^ (srow & 7)) * 8;   // pre-swizzled k-chunk (shorts)
  const int swb = (r15 & 7) * 8;
  const int NT = DM / 64;                       // 16 K-tiles

#pragma unroll
  for (int i = 0; i < 4; i++)
#pragma unroll
    for (int j = 0; j < 4; j++) acc[i][j] = (f32x4)0.0f;

  auto stage = [&](int kt, int bufi) {
    const int k0 = kt * 64;
    short* Ad = As + bufi * 8192 + t * 8;
    short* Bd = Bs + bufi * 8192 + t * 8;
#pragma unroll
    for (int i = 0; i < 4; i++) {
      async16(A  + (size_t)(m0 + srow + 32 * i) * DM + k0 + spg, Ad + i * 2048);
      async16(Bh + (size_t)(n0 + srow + 32 * i) * DM + k0 + spg, Bd + i * 2048);
    }
  };

  stage(0, 0);        // 8 loads
  stage(1, 1);        // 8 loads  (16 outstanding)

  for (int kt = 0; kt < NT; kt++) {
    const int cur = kt & 1;
    // ---- barrier 1: buf[cur] fully staged, globally ----
    if (kt + 1 < NT) { S_VMCNT(8); } else { S_VMCNT(0); }
    __builtin_amdgcn_s_barrier();
    __builtin_amdgcn_sched_barrier(0);          // reads must not hoist above barrier

    const short* Ab = As + cur * 8192;
    const short* Bb = Bs + cur * 8192;
    bf16x8 ah[4][2], bh[4][2];
#pragma unroll
    for (int mt = 0; mt < 4; mt++) {
      const int ro = (wm + mt * 16 + r15) * 64;
#pragma unroll
      for (int ks = 0; ks < 2; ks++)
        ah[mt][ks] = *(const bf16x8*)&Ab[ro + (((ks * 4 + quad) * 8) ^ swb)];
    }
#pragma unroll
    for (int nt = 0; nt < 4; nt++) {
      const int ro = (wn + nt * 16 + r15) * 64;
#pragma unroll
      for (int ks = 0; ks < 2; ks++)
        bh[nt][ks] = *(const bf16x8*)&Bb[ro + (((ks * 4 + quad) * 8) ^ swb)];
    }

    __builtin_amdgcn_s_setprio(1);
#pragma unroll
    for (int mt = 0; mt < 4; mt++)
#pragma unroll
      for (int nt = 0; nt < 4; nt++) {
        acc[mt][nt] = __builtin_amdgcn_mfma_f32_16x16x32_bf16(ah[mt][0], bh[nt][0], acc[mt][nt], 0, 0, 0);
        acc[mt][nt] = __builtin_amdgcn_mfma_f32_16x16x32_bf16(ah[mt][1], bh[nt][1], acc[mt][nt], 0, 0, 0);
      }
    __builtin_amdgcn_s_setprio(0);

    // ---- barrier 2: all waves' ds_reads of buf[cur] complete -> restage ----
    __builtin_amdgcn_s_barrier();
    __builtin_amdgcn_sched_barrier(0);          // stage must not hoist above barrier
    if (kt + 2 < NT) stage(kt + 2, cur);
  }
}

// ---------------------------------------------------------------------------
// Fused Q/K/V projection, FLAT grid of 1536 blocks (T1 XCD co-location):
//   gid = x*192 + y*3 + z  ->  gid%8 == (3y+z)%8 for all 8 x-blocks,
// so the A-panel (row-panel of xh/kvh) sharers run on ONE XCD's L2.
// Q/K: bf16 row-major (Q scaled by QSCALE); V: bf16 transposed +
// sigma-permuted cols for attn.
// ---------------------------------------------------------------------------
__global__ __launch_bounds__(256, 2)
void gemm_qkv(const short* __restrict__ xh, const short* __restrict__ kvh,
              const short* __restrict__ Wqh, const short* __restrict__ Wkh,
              const short* __restrict__ Wvh,
              short* __restrict__ Qh, short* __restrict__ Kh, short* __restrict__ Vt)
{
  __shared__ short As[2][8192];
  __shared__ short Bs[2][8192];
  const int gid = blockIdx.x;          // 0..1535
  const int xblk = gid / 192;          // n-block 0..7
  const int rem  = gid - xblk * 192;
  const int yblk = rem / 3;            // m-block 0..63
  const int z    = rem - yblk * 3;     // {Q,K,V}
  const short* A  = (z == 0) ? xh : kvh;
  const short* Bm = (z == 0) ? Wqh : (z == 1) ? Wkh : Wvh;
  const int m0 = yblk * 128, n0 = xblk * 128;

  f32x4 acc[4][4];
  gemm_core(A, Bm, &As[0][0], &Bs[0][0], m0, n0, acc);

  const int t = threadIdx.x, lane = t & 63, w = t >> 6;
  const int r15 = lane & 15, quad = lane >> 4;
  const int wm = (w & 1) * 64, wn = (w >> 1) * 64;

  if (z < 2) {
    short* Cp = (z == 0) ? Qh : Kh;
    const float scale = (z == 0) ? QSCALE : 1.0f;
#pragma unroll
    for (int mt = 0; mt < 4; mt++)
#pragma unroll
      for (int nt = 0; nt < 4; nt++)
#pragma unroll
        for (int reg = 0; reg < 4; reg++) {
          int m = m0 + wm + mt * 16 + quad * 4 + reg;
          int n = n0 + wn + nt * 16 + r15;
          Cp[(size_t)m * DM + n] = f2bf(acc[mt][nt][reg] * scale);
        }
  } else {
    // V: [b][d][sigma(s)], sigma within each 64-block: (kl&15)*4 + kl>>4
#pragma unroll
    for (int mt = 0; mt < 4; mt++)
#pragma unroll
      for (int nt = 0; nt < 4; nt++)
#pragma unroll
        for (int reg = 0; reg < 4; reg++) {
          int m = m0 + wm + mt * 16 + quad * 4 + reg;
          int n = n0 + wn + nt * 16 + r15;
          int s = m & (SEQ - 1), kl = s & 63;
          int sp = (s & ~63) + ((kl & 15) * 4 + (kl >> 4));
          Vt[((size_t)(m >> 11) * DM + n) * SEQ + sp] = f2bf(acc[mt][nt][reg]);
        }
  }
}

// Output projection: ctx(bf16) x Wo^T -> fp32 row-major.  FLAT grid of 512:
//   gid = x*64 + y  ->  gid%8 == y%8 for all 8 x-blocks (A-panel co-location).
__global__ __launch_bounds__(256, 2)
void gemm_out(const short* __restrict__ ctx, const short* __restrict__ Woh,
              float* __restrict__ out)
{
  __shared__ short As[2][8192];
  __shared__ short Bs[2][8192];
  const int gid = blockIdx.x;          // 0..511
  const int xblk = gid >> 6;           // n-block 0..7
  const int yblk = gid & 63;           // m-block 0..63
  const int m0 = yblk * 128, n0 = xblk * 128;
  f32x4 acc[4][4];
  gemm_core(ctx, Woh, &As[0][0], &Bs[0][0], m0, n0, acc);

  const int t = threadIdx.x, lane = t & 63, w = t >> 6;
  const int r15 = lane & 15, quad = lane >> 4;
  const int wm = (w & 1) * 64, wn = (w >> 1) * 64;
#pragma unroll
  for (int mt = 0; mt < 4; mt++)
#pragma unroll
    for (int nt = 0; nt < 4; nt++)
#pragma unroll
      for (int reg = 0; reg < 4; reg++) {
        int m = m0 + wm + mt * 16 + quad * 4 + reg;
        int n = n0 + wn + nt * 16 + r15;
        out[(size_t)m * DM + n] = acc[mt][nt][reg];
      }
}

// ---------------------------------------------------------------------------
// Causal flash attention. Q (pre-scaled) bf16 [B*SEQ,DM]; K bf16 [B*SEQ,DM];
// V bf16 [(b*DM+d)][sigma(s)]; out ctx bf16.
// Grid (64,16): K/V-panel sharers (same x, varying y) share lin%8 -> same XCD.
// Skeleton: double-buffered async K/V staging via global_load_lds, one
// barrier per k-tile, heavy-first (qt = 15-y), 3 blocks/CU.
// R7: bf16 packing via v_cvt_pk_bf16_f32 (1 op per score-pair, RNE) replaces
// shift/or truncation pack (3 ops per pair) — VALUBusy was 45% (r0 counters),
// the softmax-finish VALU chain is the dominant non-MFMA cost.
// ---------------------------------------------------------------------------
__global__ __launch_bounds__(256, 3)
void attn(const short* __restrict__ Qh_g, const short* __restrict__ Kh_g,
          const short* __restrict__ Vt_g, short* __restrict__ ctx)
{
  __shared__ short KV[2][2 * 4096];   // [Kh | V], 16 KB per buffer
  __shared__ short Plds[4][32][72];

  const int t = threadIdx.x, lane = t & 63, w = t >> 6;
  const int r15 = lane & 15, quad = lane >> 4;
  const int bh = blockIdx.x, b = bh >> 4, h = bh & 15;
  const int qt = 15 - blockIdx.y;     // heavy-first dispatch
  const int qw = qt * 128 + w * 32;
  const int nkt = 2 * qt + 2;

  const int srow = t >> 3, spg = (t & 7) ^ (srow & 7);
  const int swb = (r15 & 7) * 8;

  const bf16x8 ones = {0x3F80, 0x3F80, 0x3F80, 0x3F80, 0x3F80, 0x3F80, 0x3F80, 0x3F80};

  // Q fragments (A layout: m = lane&15, k = quad*8 + j)
  bf16x8 qh[2][2];
#pragma unroll
  for (int mt = 0; mt < 2; mt++)
#pragma unroll
    for (int ks = 0; ks < 2; ks++)
      qh[mt][ks] = *(const bf16x8*)(Qh_g + (size_t)(b * SEQ + qw + mt * 16 + r15) * DM
                                    + h * HD + ks * 32 + quad * 8);

  f32x4 o[2][4], ol[2];
#pragma unroll
  for (int mt = 0; mt < 2; mt++) {
    ol[mt] = (f32x4)0.0f;
#pragma unroll
    for (int dt = 0; dt < 4; dt++) o[mt][dt] = (f32x4)0.0f;
  }

  auto stage = [&](int kt, int bufi) {
    short* L = &KV[bufi][0];
    size_t kro = (size_t)(b * SEQ + kt * 64 + srow) * DM + h * HD + spg * 8;
    async16(Kh_g + kro,           L + t * 8);
    async16(Kh_g + kro + 32 * DM, L + 2048 + t * 8);
    size_t vro = (size_t)(b * DM + h * HD + srow) * SEQ + kt * 64 + spg * 8;
    async16(Vt_g + vro,            L + 4096 + t * 8);
    async16(Vt_g + vro + 32 * SEQ, L + 6144 + t * 8);
  };

  stage(0, 0);

  for (int kt = 0; kt < nkt; kt++) {
    __syncthreads();                      // buf[kt&1] staged; prior compute done
    if (kt + 1 < nkt) stage(kt + 1, (kt + 1) & 1);
    const short* L = &KV[kt & 1][0];
    const int k0 = kt * 64;
    if (k0 > qw + 31) continue;           // fully masked for this wave

    // ---- S = Q K^T (Q pre-scaled by QSCALE) ----
    f32x4 s[2][4];
#pragma unroll
    for (int nt = 0; nt < 4; nt++) {
      const int kb = k0 + nt * 16;
      if (kb <= qw + 31) {                // wave-uniform
        const int ro = (nt * 16 + r15) * 64;
        bf16x8 kh0 = *(const bf16x8*)&L[ro + ((quad * 8) ^ swb)];
        bf16x8 kh1 = *(const bf16x8*)&L[ro + (((4 + quad) * 8) ^ swb)];
        f32x4 a1 = (f32x4)0.0f;
        a1 = __builtin_amdgcn_mfma_f32_16x16x32_bf16(qh[1][0], kh0, a1, 0, 0, 0);
        a1 = __builtin_amdgcn_mfma_f32_16x16x32_bf16(qh[1][1], kh1, a1, 0, 0, 0);
        s[1][nt] = a1;
        if (kb <= qw + 15) {
          f32x4 a0 = (f32x4)0.0f;
          a0 = __builtin_amdgcn_mfma_f32_16x16x32_bf16(qh[0][0], kh0, a0, 0, 0, 0);
          a0 = __builtin_amdgcn_mfma_f32_16x16x32_bf16(qh[0][1], kh1, a0, 0, 0, 0);
          s[0][nt] = a0;
        } else {
          s[0][nt] = (f32x4)(-3e38f);     // fully masked sub-tile -> exp2 -> 0
        }
      } else {
        s[0][nt] = (f32x4)(-3e38f);
        s[1][nt] = (f32x4)(-3e38f);
      }
    }

    // ---- exp2 (+ mask only on diagonal tiles) + cvt_pk pack ----
    unsigned up[2][4][2];                 // [mt][r][pair]: packed bf16, col = r15*4+nt
    if (k0 + 63 <= qw) {                  // interior: zero mask code
#pragma unroll
      for (int mt = 0; mt < 2; mt++)
#pragma unroll
        for (int r = 0; r < 4; r++)
#pragma unroll
          for (int p = 0; p < 2; p++) {
            float lo = __builtin_amdgcn_exp2f(s[mt][2 * p][r]);
            float hi = __builtin_amdgcn_exp2f(s[mt][2 * p + 1][r]);
            up[mt][r][p] = cvt_pk_bf16(lo, hi);
          }
    } else {                              // diagonal: per-score causal mask
#pragma unroll
      for (int mt = 0; mt < 2; mt++)
#pragma unroll
        for (int r = 0; r < 4; r++) {
          const int qg = qw + mt * 16 + quad * 4 + r;
#pragma unroll
          for (int p = 0; p < 2; p++) {
            float lo = __builtin_amdgcn_exp2f(s[mt][2 * p][r]);
            float hi = __builtin_amdgcn_exp2f(s[mt][2 * p + 1][r]);
            lo = ((k0 + (2 * p) * 16 + r15) > qg) ? 0.0f : lo;
            hi = ((k0 + (2 * p + 1) * 16 + r15) > qg) ? 0.0f : hi;
            up[mt][r][p] = cvt_pk_bf16(lo, hi);
          }
        }
    }

    // ---- P -> LDS (per-wave, packed b64, sigma col order) ----
#pragma unroll
    for (int mt = 0; mt < 2; mt++)
#pragma unroll
      for (int r = 0; r < 4; r++)
        *(int2*)&Plds[w][mt * 16 + quad * 4 + r][r15 * 4] =
            make_int2((int)up[mt][r][0], (int)up[mt][r][1]);

    // ---- O += P V ; l += P . ones ----
#pragma unroll
    for (int ks = 0; ks < 2; ks++) {
      bf16x8 pa0 = *(const bf16x8*)&Plds[w][r15][ks * 32 + quad * 8];
      bf16x8 pa1 = *(const bf16x8*)&Plds[w][16 + r15][ks * 32 + quad * 8];
      ol[0] = __builtin_amdgcn_mfma_f32_16x16x32_bf16(pa0, ones, ol[0], 0, 0, 0);
      ol[1] = __builtin_amdgcn_mfma_f32_16x16x32_bf16(pa1, ones, ol[1], 0, 0, 0);
#pragma unroll
      for (int dt = 0; dt < 4; dt++) {
        bf16x8 vb = *(const bf16x8*)&L[4096 + (dt * 16 + r15) * 64 + (((ks * 4 + quad) * 8) ^ swb)];
        o[0][dt] = __builtin_amdgcn_mfma_f32_16x16x32_bf16(pa0, vb, o[0][dt], 0, 0, 0);
        o[1][dt] = __builtin_amdgcn_mfma_f32_16x16x32_bf16(pa1, vb, o[1][dt], 0, 0, 0);
      }
    }
  }

  // ---- epilogue: O / l -> ctx (bf16, RNE) ----
#pragma unroll
  for (int mt = 0; mt < 2; mt++)
#pragma unroll
    for (int r = 0; r < 4; r++) {
      float inv = 1.0f / ol[mt][r];
      int qrow = qw + mt * 16 + quad * 4 + r;
#pragma unroll
      for (int dt = 0; dt < 4; dt++)
        ctx[((size_t)(b * SEQ + qrow)) * DM + h * HD + dt * 16 + r15] =
            f2bf(o[mt][dt][r] * inv);
    }
}

// ---------------------------------------------------------------------------
extern "C" void kernel_launch(void* const* d_in, const int* in_sizes, int n_in,
                              void* d_out, int out_size, void* d_ws, size_t ws_size,
                              hipStream_t stream)
{
  const float* x  = (const float*)d_in[0];
  const float* kv = (const float*)d_in[1];
  // d_in[2] = causal mask, hardcoded
  const float* Wq = (const float*)d_in[3];
  const float* Wk = (const float*)d_in[4];
  const float* Wv = (const float*)d_in[5];
  const float* Wo = (const float*)d_in[6];

  char* ws = (char*)d_ws;
  const size_t SZ  = (size_t)BATCH * SEQ * DM * sizeof(short);  // 16 MB
  const size_t WSZ = (size_t)DM * DM * sizeof(short);           // 2 MB
  short* xh  = (short*)(ws + 0 * SZ);   // dead after Q-GEMM; reused as ctx
  short* kvh = (short*)(ws + 1 * SZ);
  short* Qh  = (short*)(ws + 2 * SZ);
  short* Kh  = (short*)(ws + 3 * SZ);
  short* Vt  = (short*)(ws + 4 * SZ);
  short* ctx = (short*)(ws + 0 * SZ);
  char*  wb  = ws + 5 * SZ;
  short* Wqh = (short*)(wb + 0 * WSZ);
  short* Wkh = (short*)(wb + 1 * WSZ);
  short* Wvh = (short*)(wb + 2 * WSZ);
  short* Woh = (short*)(wb + 3 * WSZ);  // total ws use: 88 MB

  conv_all<<<20480, 256, 0, stream>>>(x, kv, Wq, Wk, Wv, Wo,
                                      xh, kvh, Wqh, Wkh, Wvh, Woh);

  // flat 1536: gid = x*192 + y*3 + z -> A-panel sharers co-located per XCD
  gemm_qkv<<<1536, 256, 0, stream>>>(xh, kvh, Wqh, Wkh, Wvh, Qh, Kh, Vt);

  dim3 ga(NH * BATCH, 16);                   // x = b*16+h (XCD locality), y -> qt
  attn<<<ga, 256, 0, stream>>>(Qh, Kh, Vt, ctx);

  // flat 512: gid = x*64 + y -> A-panel (ctx) sharers co-located per XCD
  gemm_out<<<512, 256, 0, stream>>>(ctx, Woh, (float*)d_out);
}